// Round 4
// baseline (365.995 us; speedup 1.0000x reference)
//
#include <hip/hip_runtime.h>

typedef __attribute__((ext_vector_type(4))) short short4v;
typedef __attribute__((ext_vector_type(8))) short short8;
typedef __attribute__((ext_vector_type(4))) float floatx4;

#define NB 16384
#define TT 24
#define HH 128
#define LDA 40   // padded LDS stride for 32-wide k tiles
#define LDH 136  // padded LDS stride for h (128 + 8)

__device__ __forceinline__ float bf2f(unsigned short u) {
    union { unsigned int i; float f; } v; v.i = ((unsigned int)u) << 16; return v.f;
}
__device__ __forceinline__ unsigned short f2bf(float f) {
    union { float f; unsigned int i; } v; v.f = f;
    unsigned int x = v.i;
    unsigned int r = (x + 0x7fffu + ((x >> 16) & 1u)) >> 16;
    return (unsigned short)r;
}
__device__ __forceinline__ float fsig(float x) {
    return __fdividef(1.f, 1.f + __expf(-x));
}
__device__ __forceinline__ float ftanh(float x) {
    x = fminf(15.f, fmaxf(-15.f, x));
    float e = __expf(2.f * x);
    return __fdividef(e - 1.f, e + 1.f);
}

// dtype-dispatched loads: element offset semantics, either f32 or bf16 storage.
__device__ __forceinline__ float ldv(const void* base, size_t i, int isf32) {
    return isf32 ? ((const float*)base)[i] : bf2f(((const unsigned short*)base)[i]);
}
__device__ __forceinline__ short8 ld8(const void* base, size_t eoff, int isf32) {
    short8 r;
    if (isf32) {
        const float* p = (const float*)base + eoff;
        floatx4 a = *(const floatx4*)p;
        floatx4 b = *(const floatx4*)(p + 4);
        r[0] = (short)f2bf(a[0]); r[1] = (short)f2bf(a[1]);
        r[2] = (short)f2bf(a[2]); r[3] = (short)f2bf(a[3]);
        r[4] = (short)f2bf(b[0]); r[5] = (short)f2bf(b[1]);
        r[6] = (short)f2bf(b[2]); r[7] = (short)f2bf(b[3]);
    } else {
        r = *(const short8*)((const unsigned short*)base + eoff);
    }
    return r;
}
__device__ __forceinline__ short4v ld4(const void* base, size_t eoff, int isf32) {
    short4v r;
    if (isf32) {
        const float* p = (const float*)base + eoff;
        floatx4 a = *(const floatx4*)p;
        r[0] = (short)f2bf(a[0]); r[1] = (short)f2bf(a[1]);
        r[2] = (short)f2bf(a[2]); r[3] = (short)f2bf(a[3]);
    } else {
        r = *(const short4v*)((const unsigned short*)base + eoff);
    }
    return r;
}

// One fused kernel: 256 blocks x 512 threads; block owns 64 batch rows.
// Phase 0: probe input dtype (f32 vs bf16) from enc's even u16 lanes.
// Phase 1: gi = zx@W_ih[:, :1056].T (+h0 = zx@W_dh.T) via MFMA, K=1056 -> registers.
// Phase 2: 24-step GRU recurrence, W_hh resident in VGPRs, h in LDS (bf16).
// OUTPUT IS FLOAT32 (reference returns f32; the exact-454.0 stds error across
// rounds proved the harness reads f32 and our u16 writes covered half the buffer).
__global__ __launch_bounds__(512, 2) void k_fused(
    const void* __restrict__ last, const void* __restrict__ enc,
    const void* __restrict__ zin, const void* __restrict__ sg,
    const void* __restrict__ fut, const void* __restrict__ W_dh,
    const void* __restrict__ b_dh, const void* __restrict__ W_vel,
    const void* __restrict__ b_vel, const void* __restrict__ W_ih,
    const void* __restrict__ b_ih, const void* __restrict__ W_hh,
    const void* __restrict__ b_hh, const void* __restrict__ W_mu,
    const void* __restrict__ b_mu, const void* __restrict__ W_std,
    const void* __restrict__ b_std, float* __restrict__ out) {
    __shared__ unsigned short As[64 * LDA];
    __shared__ unsigned short h_lds[64 * LDH];
    __shared__ float a_lds[64][2];
    __shared__ float rel_lds[64][2];
    __shared__ float wmu[2][HH], wstd[2][HH];
    __shared__ float bmuv[2], bstdv[2];

    const int tid = threadIdx.x;
    const int w = tid >> 6, lane = tid & 63;
    const int col = lane & 15, q = lane >> 4;
    const int b0 = blockIdx.x * 64;
    const int jc = w * 16 + col;  // this wave's 16-col slice index, 0..127

    // ---------------- phase 0: dtype probe (wave-uniform) ----
    int isf32;
    {
        const unsigned short* pu = (const unsigned short*)enc;
        unsigned short s = pu[(size_t)2 * (size_t)lane * 131072];
        int e = (s >> 7) & 0xFF;
        unsigned long long huge = __ballot(e >= 143);
        isf32 = (huge != 0ull) ? 1 : 0;
    }

    // stage mu/std weights (f32) into LDS
    if (tid < 256) { int c = tid >> 7, k = tid & 127; wmu[c][k] = ldv(W_mu, c * HH + k, isf32); }
    else { int t2 = tid - 256; int c = t2 >> 7, k = t2 & 127; wstd[c][k] = ldv(W_std, c * HH + k, isf32); }
    if (tid < 2) { bmuv[tid] = ldv(b_mu, tid, isf32); bstdv[tid] = ldv(b_std, tid, isf32); }

    // a0 = last_obs @ W_vel.T + b_vel ; rel = (sg - last[:, :2]) / 4.8
    if (tid < 128) {
        int row = tid >> 1, c = tid & 1;
        int b = b0 + row;
        float s = ldv(b_vel, c, isf32);
#pragma unroll
        for (int s2 = 0; s2 < 6; s2++)
            s += ldv(last, b * 6 + s2, isf32) * ldv(W_vel, c * 6 + s2, isf32);
        a_lds[row][c] = s;
        rel_lds[row][c] = (ldv(sg, b * 2 + c, isf32) - ldv(last, b * 6 + c, isf32)) * (1.f / 4.8f);
    }

    // ---------------- phase 1: K=1056 GEMM into registers ----------------
    floatx4 acc2[4][4];  // [mt][gg]: gg=0..2 gates, gg=3 -> h0
#pragma unroll
    for (int i = 0; i < 4; i++)
#pragma unroll
        for (int j = 0; j < 4; j++) acc2[i][j] = (floatx4){0.f, 0.f, 0.f, 0.f};

    const int arow = tid >> 3, koff = (tid & 7) * 4;  // A staging: 64 rows x 32 k

    size_t woff[4];
#pragma unroll
    for (int g = 0; g < 3; g++) woff[g] = (size_t)(g * HH + jc) * 1060;
    const void* wbase[4] = {W_ih, W_ih, W_ih, W_dh};
    woff[3] = (size_t)jc * 1056;

    for (int ki = 0; ki < 33; ki++) {
        short4v av = (ki < 32)
            ? ld4(enc, (size_t)(b0 + arow) * 1024 + ki * 32 + koff, isf32)
            : ld4(zin, (size_t)(b0 + arow) * 32 + koff, isf32);
        __syncthreads();  // protect As reads of previous iter
        *(short4v*)(As + arow * LDA + koff) = av;
        __syncthreads();  // As visible
        short8 af[4];
#pragma unroll
        for (int mt = 0; mt < 4; mt++)
            af[mt] = *(const short8*)(As + (mt * 16 + col) * LDA + q * 8);
#pragma unroll
        for (int gg = 0; gg < 4; gg++) {
            short8 bb = ld8(wbase[gg], woff[gg] + ki * 32 + q * 8, isf32);
#pragma unroll
            for (int mt = 0; mt < 4; mt++)
                acc2[mt][gg] = __builtin_amdgcn_mfma_f32_16x16x32_bf16(
                    af[mt], bb, acc2[mt][gg], 0, 0, 0);
        }
    }

    // phase-1 epilogue -> greg / hprev registers, h0 -> LDS (bf16)
    float bihg[3], wr0g[3], wr1g[3], wa0[3], wa1[3];
    float bhh_n;
#pragma unroll
    for (int g = 0; g < 3; g++) {
        const size_t rb = (size_t)(g * HH + jc) * 1060;
        // fold b_hh into greg for r,z gates; n-gate's b_hh stays inside gh_n
        bihg[g] = ldv(b_ih, g * HH + jc, isf32) + ((g < 2) ? ldv(b_hh, g * HH + jc, isf32) : 0.f);
        wr0g[g] = ldv(W_ih, rb + 1058, isf32);
        wr1g[g] = ldv(W_ih, rb + 1059, isf32);
        wa0[g] = ldv(W_ih, rb + 1056, isf32);
        wa1[g] = ldv(W_ih, rb + 1057, isf32);
    }
    bhh_n = ldv(b_hh, 2 * HH + jc, isf32);

    float greg[4][3][4];  // [mt][gate][r]
    float hprev[4][4];    // [mt][r]
    const float bdh = ldv(b_dh, jc, isf32);
#pragma unroll
    for (int mt = 0; mt < 4; mt++) {
#pragma unroll
        for (int r = 0; r < 4; r++) {
            int blr = mt * 16 + q * 4 + r;
            float r0 = rel_lds[blr][0], r1 = rel_lds[blr][1];
#pragma unroll
            for (int g = 0; g < 3; g++)
                greg[mt][g][r] = acc2[mt][g][r] + bihg[g] + r0 * wr0g[g] + r1 * wr1g[g];
            float h0v = acc2[mt][3][r] + bdh;
            hprev[mt][r] = h0v;
            h_lds[blr * LDH + jc] = f2bf(h0v);
        }
    }

    // resident W_hh fragments: [gate][kt]
    short8 bfr[3][4];
#pragma unroll
    for (int g = 0; g < 3; g++)
#pragma unroll
        for (int kt = 0; kt < 4; kt++)
            bfr[g][kt] = ld8(W_hh, (size_t)(g * HH + jc) * HH + kt * 32 + q * 8, isf32);

    __syncthreads();  // h_lds (h0) visible to all waves

    // ---------------- phase 2: 24-step recurrence ----------------
    for (int t = 0; t < TT; t++) {
        floatx4 acc[4][3];
#pragma unroll
        for (int mt = 0; mt < 4; mt++)
#pragma unroll
            for (int g = 0; g < 3; g++) acc[mt][g] = (floatx4){0.f, 0.f, 0.f, 0.f};
#pragma unroll
        for (int kt = 0; kt < 4; kt++) {
            short8 af2[4];
#pragma unroll
            for (int mt = 0; mt < 4; mt++)
                af2[mt] = *(const short8*)(h_lds + (mt * 16 + col) * LDH + kt * 32 + q * 8);
#pragma unroll
            for (int mt = 0; mt < 4; mt++)
#pragma unroll
                for (int g = 0; g < 3; g++)
                    acc[mt][g] = __builtin_amdgcn_mfma_f32_16x16x32_bf16(
                        af2[mt], bfr[g][kt], acc[mt][g], 0, 0, 0);
        }

        // gates
#pragma unroll
        for (int mt = 0; mt < 4; mt++) {
#pragma unroll
            for (int r = 0; r < 4; r++) {
                int blr = mt * 16 + q * 4 + r;
                float a0v = a_lds[blr][0], a1v = a_lds[blr][1];
                float gir = greg[mt][0][r] + a0v * wa0[0] + a1v * wa1[0] + acc[mt][0][r];
                float giz = greg[mt][1][r] + a0v * wa0[1] + a1v * wa1[1] + acc[mt][1][r];
                float gin = greg[mt][2][r] + a0v * wa0[2] + a1v * wa1[2];
                float ghn = acc[mt][2][r] + bhh_n;
                float rg = fsig(gir);
                float zg = fsig(giz);
                float ng = ftanh(gin + rg * ghn);
                hprev[mt][r] = (1.f - zg) * ng + zg * hprev[mt][r];
            }
        }

        __syncthreads();  // all reads of h_lds / a_lds done

        // write new h, stage next a
#pragma unroll
        for (int mt = 0; mt < 4; mt++)
#pragma unroll
            for (int r = 0; r < 4; r++)
                h_lds[(mt * 16 + q * 4 + r) * LDH + jc] = f2bf(hprev[mt][r]);
        if (tid < 128) {
            int row = tid >> 1, c = tid & 1;
            int b = b0 + row;
            a_lds[row][c] = ldv(fut, ((size_t)t * NB + b) * 6 + 2 + c, isf32);
        }

        __syncthreads();

        // mu/std epilogue: 256 tasks (row,c,kind), 2 threads per task split over k
        {
            int task = tid >> 1, part = tid & 1;
            int row = task >> 2, c = (task >> 1) & 1, kind = task & 1;
            const float* wv = kind ? wstd[c] : wmu[c];
            const unsigned short* hrow = h_lds + row * LDH + part * 64;
            float sum = 0.f;
#pragma unroll
            for (int k = 0; k < 64; k++) sum += bf2f(hrow[k]) * wv[part * 64 + k];
            sum += __shfl_xor(sum, 1);
            if (part == 0) {
                float val = sum + (kind ? bstdv[c] : bmuv[c]);
                if (kind) val = __expf(0.5f * val);
                out[(size_t)kind * (TT * NB * 2) + ((size_t)t * NB + (b0 + row)) * 2 + c] = val;
            }
        }
    }
}

extern "C" void kernel_launch(void* const* d_in, const int* in_sizes, int n_in,
                              void* d_out, int out_size, void* d_ws, size_t ws_size,
                              hipStream_t stream) {
    (void)d_ws; (void)ws_size; (void)in_sizes; (void)n_in; (void)out_size;
    float* out = (float*)d_out;

    k_fused<<<256, 512, 0, stream>>>(d_in[0], d_in[1], d_in[2], d_in[3], d_in[4],
                                     d_in[5], d_in[6], d_in[7], d_in[8], d_in[9],
                                     d_in[10], d_in[11], d_in[12], d_in[13], d_in[14],
                                     d_in[15], d_in[16], out);
}